// Round 4
// baseline (179.548 us; speedup 1.0000x reference)
//
#include <hip/hip_runtime.h>
#include <stdint.h>

// Problem constants (match reference)
#define Bn   256
#define Dn   2048
#define Sn   8
#define ON   1000

// Tiling: one block per (o-chunk, subject), full K per block, single dispatch.
#define ROWS 64             // max samples per subject (binomial mean 32; +6 sigma)
#define OT   32             // output columns per block -> 32 oc x 8 s = 256 blocks = 1/CU
#define CK   256            // k per chunk
#define NCH  (Dn / CK)      // 8 chunks
#define LDK  (CK + 8)       // LDS row stride (ushorts) = 264; 132 words = 4 mod 32

typedef short v8s __attribute__((ext_vector_type(8)));
typedef float v4f __attribute__((ext_vector_type(4)));

// fp32 -> bf16 round-to-nearest-even
static __device__ __forceinline__ short f2bf(float f) {
    union { float f; uint32_t u; } v; v.f = f;
    uint32_t u = v.u;
    u += 0x7FFFu + ((u >> 16) & 1u);
    return (short)(u >> 16);
}

__global__ __launch_bounds__(256, 1) void fused_kernel(const float* __restrict__ x,
                                                       const int* __restrict__ sid,
                                                       const float* __restrict__ W,
                                                       const float* __restrict__ bias,
                                                       float* __restrict__ out) {
    __shared__ unsigned short Ash[2][ROWS * LDK];   // A[m][k] bf16
    __shared__ unsigned short Bsh[2][OT * LDK];     // B[o][k] bf16
    __shared__ unsigned long long bmask[4];
    __shared__ int rows_l[ROWS];

    const int oc = blockIdx.x;   // 0..31
    const int s  = blockIdx.y;   // 0..7
    const int o0 = oc * OT;
    const int t  = threadIdx.x;
    const int lane = t & 63;
    const int wave = t >> 6;

    // ---- bucket samples of subject s via ballot (deterministic, no atomics) ----
    const bool match = (sid[t] == s);
    const unsigned long long m = __ballot(match);
    if (lane == 0) bmask[wave] = m;
    if (t < ROWS) rows_l[t] = -1;
    __syncthreads();
    if (match) {
        int pos = __popcll(m & ((1ull << lane) - 1ull));
        for (int w = 0; w < wave; ++w) pos += __popcll(bmask[w]);
        if (pos < ROWS) rows_l[pos] = t;
    }
    __syncthreads();

    // ---- staging assignments ----
    // A: thread t covers row (t>>2), k-subgroup (t&3); per chunk j=0..7: k = j*32 + (t&3)*8
    const int arow = t >> 2;
    const int ag   = t & 3;
    const int xrow = rows_l[arow];
    const float* xp = (xrow >= 0) ? (x + (size_t)xrow * Dn + ag * 8) : x;  // garbage rows dropped at store
    const int aoff = arow * LDK + ag * 8;

    // B: thread t covers o column o0+(t&31), k-rows kg*8..kg*8+7 per 64-k group (kg = t>>5).
    // Wave-coalesced 128B along o, cacheline-aligned (o0*4 = oc*128).
    int og = o0 + (t & 31); if (og > ON - 1) og = ON - 1;   // clamp; dropped at store
    const int kg = t >> 5;
    const float* wp = W + (size_t)s * Dn * ON + (size_t)(kg * 8) * ON + og;
    const int boff = (t & 31) * LDK + kg * 8;

    // ---- chunk prefetch registers (depth-2 ring) ----
    float4 fa[2][16];   // 16 float4 per chunk: j=0..7 -> (xp + c*CK + j*32) and +4
    float  fb[2][32];   // 32 scalars per chunk: j=0..3, e=0..7 -> k = c*CK + j*64 + e (wp pre-offset by kg*8)

#define LOAD_CHUNK(slot, c)                                                          \
    {                                                                                \
        _Pragma("unroll")                                                            \
        for (int j = 0; j < 8; j++) {                                                \
            fa[slot][2*j]   = *(const float4*)(xp + (c) * CK + j * 32);              \
            fa[slot][2*j+1] = *(const float4*)(xp + (c) * CK + j * 32 + 4);          \
        }                                                                            \
        _Pragma("unroll")                                                            \
        for (int j = 0; j < 4; j++)                                                  \
            _Pragma("unroll")                                                        \
            for (int e = 0; e < 8; e++)                                              \
                fb[slot][j*8+e] = wp[(size_t)((c) * CK + j * 64 + e) * ON];          \
    }

    // ---- compute-side constants ----
    const int lo16 = lane & 15;
    const int quad = lane >> 4;
    const int ar_off = (wave * 16 + lo16) * LDK;

    v4f acc[2];
    acc[0] = (v4f){0.f, 0.f, 0.f, 0.f};
    acc[1] = (v4f){0.f, 0.f, 0.f, 0.f};

    // ---- prologue: chunks 0 and 1 in flight ----
    LOAD_CHUNK(0, 0)
    LOAD_CHUNK(1, 1)

    for (int c = 0; c < NCH; ++c) {
        const int sl = c & 1;

        // convert + store chunk c (waits only on its own loads via register deps)
        unsigned short* Ab = &Ash[sl][0];
        unsigned short* Bb = &Bsh[sl][0];
#pragma unroll
        for (int j = 0; j < 8; j++) {
            const float4 f0 = fa[sl][2*j], f1 = fa[sl][2*j+1];
            v8s av;
            av[0] = f2bf(f0.x); av[1] = f2bf(f0.y); av[2] = f2bf(f0.z); av[3] = f2bf(f0.w);
            av[4] = f2bf(f1.x); av[5] = f2bf(f1.y); av[6] = f2bf(f1.z); av[7] = f2bf(f1.w);
            *(v8s*)&Ab[aoff + j * 32] = av;
        }
#pragma unroll
        for (int j = 0; j < 4; j++) {
            v8s bv;
#pragma unroll
            for (int e = 0; e < 8; e++) bv[e] = f2bf(fb[sl][j*8+e]);
            *(v8s*)&Bb[boff + j * 64] = bv;
        }

        __syncthreads();   // drains vmcnt: c+2 loads were issued a full convert+compute ago -> ~0 residual

        // issue chunk c+2 loads NOW (post-barrier): they stay in flight through
        // compute(c) + convert(c+1) before the next barrier drains them.
        if (c + 2 < NCH) LOAD_CHUNK(sl, c + 2)

        // ---- MFMA on chunk c ----
#pragma unroll
        for (int it = 0; it < 8; ++it) {
            const v8s af = *(const v8s*)&Ab[ar_off + it * 32 + quad * 8];
#pragma unroll
            for (int nt = 0; nt < 2; nt++) {
                const v8s bf = *(const v8s*)&Bb[(nt * 16 + lo16) * LDK + it * 32 + quad * 8];
                acc[nt] = __builtin_amdgcn_mfma_f32_16x16x32_bf16(af, bf, acc[nt], 0, 0, 0);
            }
        }
        // buffer sl is rewritten at iter c+2, after barrier c+1 -> no extra barrier needed
    }
#undef LOAD_CHUNK

    // ---- epilogue: C/D layout col=lane&15, row=quad*4+reg; bias fused, direct store ----
    const int er0 = wave * 16 + quad * 4;
#pragma unroll
    for (int nt = 0; nt < 2; nt++) {
        const int o = o0 + nt * 16 + lo16;
        if (o < ON) {
            const float bv = bias[(size_t)s * ON + o];
#pragma unroll
            for (int r = 0; r < 4; r++) {
                const int bi = rows_l[er0 + r];
                if (bi >= 0) out[(size_t)bi * ON + o] = acc[nt][r] + bv;
            }
        }
    }
}

extern "C" void kernel_launch(void* const* d_in, const int* in_sizes, int n_in,
                              void* d_out, int out_size, void* d_ws, size_t ws_size,
                              hipStream_t stream) {
    const float* x    = (const float*)d_in[0];
    const int*   sid  = (const int*)d_in[1];
    const float* W    = (const float*)d_in[2];
    const float* bias = (const float*)d_in[3];
    float*       out  = (float*)d_out;

    fused_kernel<<<dim3(32, Sn), dim3(256), 0, stream>>>(x, sid, W, bias, out);
}

// Round 5
// 112.080 us; speedup vs baseline: 1.6020x; 1.6020x over previous
//
#include <hip/hip_runtime.h>
#include <stdint.h>

// Problem constants (match reference)
#define Bn   256
#define Dn   2048
#define Sn   8
#define ON   1000

// Tiling: one block per (o-chunk, subject), full K per block, single dispatch.
#define ROWS 64             // max samples per subject (binomial mean 32; +6 sigma)
#define OT   32             // output columns per block -> 32 oc x 8 s = 256 blocks = 1/CU
#define CK   256            // k per chunk
#define NCH  (Dn / CK)      // 8 chunks
#define LDK  (CK + 8)       // LDS row stride (ushorts) = 264; 132 words = 4 mod 32

typedef short v8s __attribute__((ext_vector_type(8)));
typedef float v4f __attribute__((ext_vector_type(4)));

// fp32 -> bf16 round-to-nearest-even
static __device__ __forceinline__ short f2bf(float f) {
    union { float f; uint32_t u; } v; v.f = f;
    uint32_t u = v.u;
    u += 0x7FFFu + ((u >> 16) & 1u);
    return (short)(u >> 16);
}

__global__ __launch_bounds__(256, 1) void fused_kernel(const float* __restrict__ x,
                                                       const int* __restrict__ sid,
                                                       const float* __restrict__ W,
                                                       const float* __restrict__ bias,
                                                       float* __restrict__ out) {
    __shared__ unsigned short Ash[2][ROWS * LDK];   // A[m][k] bf16
    __shared__ unsigned short Bsh[2][OT * LDK];     // B[o][k] bf16
    __shared__ unsigned long long bmask[4];
    __shared__ int rows_l[ROWS];

    const int oc = blockIdx.x;   // 0..31
    const int s  = blockIdx.y;   // 0..7
    const int o0 = oc * OT;
    const int t  = threadIdx.x;
    const int lane = t & 63;
    const int wave = t >> 6;

    // ---- bucket samples of subject s via ballot (deterministic, no atomics) ----
    const bool match = (sid[t] == s);
    const unsigned long long m = __ballot(match);
    if (lane == 0) bmask[wave] = m;
    if (t < ROWS) rows_l[t] = -1;
    __syncthreads();
    if (match) {
        int pos = __popcll(m & ((1ull << lane) - 1ull));
        for (int w = 0; w < wave; ++w) pos += __popcll(bmask[w]);
        if (pos < ROWS) rows_l[pos] = t;
    }
    __syncthreads();

    // ---- staging assignments ----
    // A: thread t covers row (t>>2), k-subgroup (t&3); per chunk j=0..7: k = j*32 + (t&3)*8
    const int arow = t >> 2;
    const int ag   = t & 3;
    const int xrow = rows_l[arow];
    const float* xp = (xrow >= 0) ? (x + (size_t)xrow * Dn + ag * 8) : x;  // garbage rows dropped at store
    const int aoff = arow * LDK + ag * 8;

    // B: thread t covers o column o0+(t&31), k-rows kg*8..kg*8+7 per 64-k group (kg = t>>5).
    // Wave-coalesced 128B along o, cacheline-aligned (o0*4 = oc*128).
    int og = o0 + (t & 31); if (og > ON - 1) og = ON - 1;   // clamp; dropped at store
    const int kg = t >> 5;
    const float* wp = W + (size_t)s * Dn * ON + (size_t)(kg * 8) * ON + og;
    const int boff = (t & 31) * LDK + kg * 8;

    // ---- chunk prefetch registers (depth-2 ring; ALL indices compile-time
    //      thanks to full unroll below -> stays in VGPRs, no scratch) ----
    float4 fa[2][16];   // 16 float4 per chunk: j=0..7 -> (xp + c*CK + j*32) and +4
    float  fb[2][32];   // 32 scalars per chunk: j=0..3, e=0..7 -> k = c*CK + j*64 + e

#define LOAD_CHUNK(slot, c)                                                          \
    {                                                                                \
        _Pragma("unroll")                                                            \
        for (int j = 0; j < 8; j++) {                                                \
            fa[slot][2*j]   = *(const float4*)(xp + (c) * CK + j * 32);              \
            fa[slot][2*j+1] = *(const float4*)(xp + (c) * CK + j * 32 + 4);          \
        }                                                                            \
        _Pragma("unroll")                                                            \
        for (int j = 0; j < 4; j++)                                                  \
            _Pragma("unroll")                                                        \
            for (int e = 0; e < 8; e++)                                              \
                fb[slot][j*8+e] = wp[(size_t)((c) * CK + j * 64 + e) * ON];          \
    }

    // ---- compute-side constants ----
    const int lo16 = lane & 15;
    const int quad = lane >> 4;
    const int ar_off = (wave * 16 + lo16) * LDK;

    v4f acc[2];
    acc[0] = (v4f){0.f, 0.f, 0.f, 0.f};
    acc[1] = (v4f){0.f, 0.f, 0.f, 0.f};

    // ---- prologue: chunks 0 and 1 in flight ----
    LOAD_CHUNK(0, 0)
    LOAD_CHUNK(1, 1)

#pragma unroll   // CRITICAL: makes sl/c compile-time so fa/fb stay in registers
    for (int c = 0; c < NCH; ++c) {
        const int sl = c & 1;

        // convert + store chunk c (waits only on its own loads via register deps)
        unsigned short* Ab = &Ash[sl][0];
        unsigned short* Bb = &Bsh[sl][0];
#pragma unroll
        for (int j = 0; j < 8; j++) {
            const float4 f0 = fa[sl][2*j], f1 = fa[sl][2*j+1];
            v8s av;
            av[0] = f2bf(f0.x); av[1] = f2bf(f0.y); av[2] = f2bf(f0.z); av[3] = f2bf(f0.w);
            av[4] = f2bf(f1.x); av[5] = f2bf(f1.y); av[6] = f2bf(f1.z); av[7] = f2bf(f1.w);
            *(v8s*)&Ab[aoff + j * 32] = av;
        }
#pragma unroll
        for (int j = 0; j < 4; j++) {
            v8s bv;
#pragma unroll
            for (int e = 0; e < 8; e++) bv[e] = f2bf(fb[sl][j*8+e]);
            *(v8s*)&Bb[boff + j * 64] = bv;
        }

        __syncthreads();   // vmcnt(0) drain here: c+1's loads have been in flight
                           // since iter c-1's post-barrier -> ~0 residual wait

        // issue chunk c+2 loads NOW (post-barrier): they stay in flight through
        // MFMA(c) + convert(c+1) before the next barrier drains them.
        if (c + 2 < NCH) LOAD_CHUNK(sl, c + 2)

        // ---- MFMA on chunk c ----
#pragma unroll
        for (int it = 0; it < 8; ++it) {
            const v8s af = *(const v8s*)&Ab[ar_off + it * 32 + quad * 8];
#pragma unroll
            for (int nt = 0; nt < 2; nt++) {
                const v8s bf = *(const v8s*)&Bb[(nt * 16 + lo16) * LDK + it * 32 + quad * 8];
                acc[nt] = __builtin_amdgcn_mfma_f32_16x16x32_bf16(af, bf, acc[nt], 0, 0, 0);
            }
        }
        // buffer sl is rewritten at iter c+2 (after barrier c+1) -> no extra barrier
    }
#undef LOAD_CHUNK

    // ---- epilogue: C/D layout col=lane&15, row=quad*4+reg; bias fused, direct store ----
    const int er0 = wave * 16 + quad * 4;
#pragma unroll
    for (int nt = 0; nt < 2; nt++) {
        const int o = o0 + nt * 16 + lo16;
        if (o < ON) {
            const float bv = bias[(size_t)s * ON + o];
#pragma unroll
            for (int r = 0; r < 4; r++) {
                const int bi = rows_l[er0 + r];
                if (bi >= 0) out[(size_t)bi * ON + o] = acc[nt][r] + bv;
            }
        }
    }
}

extern "C" void kernel_launch(void* const* d_in, const int* in_sizes, int n_in,
                              void* d_out, int out_size, void* d_ws, size_t ws_size,
                              hipStream_t stream) {
    const float* x    = (const float*)d_in[0];
    const int*   sid  = (const int*)d_in[1];
    const float* W    = (const float*)d_in[2];
    const float* bias = (const float*)d_in[3];
    float*       out  = (float*)d_out;

    fused_kernel<<<dim3(32, Sn), dim3(256), 0, stream>>>(x, sid, W, bias, out);
}